// Round 1
// baseline (131.369 us; speedup 1.0000x reference)
//
#include <hip/hip_runtime.h>

#define NLOG2E -1.44269504088896340736f

typedef float f32x2 __attribute__((ext_vector_type(2)));

// Single self-contained kernel: NO workspace, NO prefold dispatch.
// Theory: the 126 us dur is dominated by harness 256-MiB workspace re-poison
// fills (2 x 42 us visible in rocprof); the kernel itself is ~20 us. Dropping
// all d_ws use tests whether those fills leave the timed path.
//
// Fold (69 floats) is computed once per block by thread 0 into LDS, then the
// proven packed-f32x2 body runs unchanged, reading constant pairs from LDS
// (uniform address -> broadcast, conflict-free).
//
// LDS layout (floats): [0:8)=uw0 [8:16)=uw1 [16:24)=ub [24:56)=w2f
//                      [56:60)=b2 [60:64)=ncl2 [64:68)=aw2 [68]=bb3
// All pair offsets even -> 8B-aligned f32x2 reads.

__global__ __launch_bounds__(256, 3) void PlaygroundModel_66365834658304_kernel(
    const float* __restrict__ x,
    const float* __restrict__ W1, const float* __restrict__ b1,
    const float* __restrict__ a1, const float* __restrict__ c1,
    const float* __restrict__ W2, const float* __restrict__ b2,
    const float* __restrict__ a2, const float* __restrict__ c2,
    const float* __restrict__ W3, const float* __restrict__ b3,
    float* __restrict__ out, int rows)
{
    __shared__ __align__(16) float Cs[70];

    if (threadIdx.x == 0) {
#pragma unroll
        for (int j = 0; j < 8; ++j) {
            float ncl = c1[j] * NLOG2E;
            Cs[j]      = W1[j]     * ncl;
            Cs[8 + j]  = W1[8 + j] * ncl;
            Cs[16 + j] = b1[j]     * ncl;
            float k1 = a1[j] / ncl;
#pragma unroll
            for (int k = 0; k < 4; ++k)
                Cs[24 + j * 4 + k] = W2[j * 4 + k] * k1;
        }
#pragma unroll
        for (int k = 0; k < 4; ++k) {
            Cs[56 + k] = b2[k];
            Cs[60 + k] = c2[k] * NLOG2E;
            Cs[64 + k] = a2[k] * W3[k];
        }
        Cs[68] = b3[0];
    }
    __syncthreads();

    const f32x2* Cp = (const f32x2*)Cs;
    // pair views: uw0 = Cp[0..3]  uw1 = Cp[4..7]  ub = Cp[8..11]
    //             w2f = Cp[12 + j*2 + kp]  b2 = Cp[28..29]
    //             ncl2 = Cp[30..31]  aw2 = Cp[32..33]
    float bb3 = Cs[68];

    int tid = blockIdx.x * blockDim.x + threadIdx.x;
    long long base = (long long)tid * 4;

    if (base + 3 < rows) {
        const float4* x4 = (const float4*)x;
        float4 p0 = x4[(size_t)tid * 2 + 0];
        float4 p1 = x4[(size_t)tid * 2 + 1];
        float X0[4] = {p0.x, p0.z, p1.x, p1.z};
        float X1[4] = {p0.y, p0.w, p1.y, p1.w};

        // stage 1: u-values, 4 rows x 4 j-pairs of pk_fma
        f32x2 u[4][4];
#pragma unroll
        for (int r = 0; r < 4; ++r) {
            f32x2 x0b = {X0[r], X0[r]};
            f32x2 x1b = {X1[r], X1[r]};
#pragma unroll
            for (int p = 0; p < 4; ++p)
                u[r][p] = __builtin_elementwise_fma(
                              x0b, Cp[p],
                              __builtin_elementwise_fma(x1b, Cp[4 + p],
                                                        Cp[8 + p]));
        }

        // stage 2: h_eff = u * rcp(1 + exp2(u)); trans scalar, rest packed
#pragma unroll
        for (int r = 0; r < 4; ++r)
#pragma unroll
            for (int p = 0; p < 4; ++p) {
                f32x2 e;
                e[0] = __builtin_amdgcn_exp2f(u[r][p][0]);
                e[1] = __builtin_amdgcn_exp2f(u[r][p][1]);
                f32x2 d = e + 1.0f;                    // pk_add
                f32x2 s;
                s[0] = __builtin_amdgcn_rcpf(d[0]);
                s[1] = __builtin_amdgcn_rcpf(d[1]);
                u[r][p] *= s;                          // pk_mul, h_eff
            }

        // stage 3: layer-2 dot-8, two k-pair accumulators per row
        f32x2 t2a[4], t2b[4];
#pragma unroll
        for (int r = 0; r < 4; ++r) {
            f32x2 ta = Cp[28], tb = Cp[29];            // b2 pairs
#pragma unroll
            for (int j = 0; j < 8; ++j) {
                float hj = u[r][j >> 1][j & 1];
                f32x2 hb = {hj, hj};
                ta = __builtin_elementwise_fma(hb, Cp[12 + j * 2 + 0], ta);
                tb = __builtin_elementwise_fma(hb, Cp[12 + j * 2 + 1], tb);
            }
            t2a[r] = ta; t2b[r] = tb;
        }

        // stage 4: second activation + final reduce, packed where possible
        float res[4];
#pragma unroll
        for (int r = 0; r < 4; ++r) {
            f32x2 u2a = Cp[30] * t2a[r];               // ncl2 pairs
            f32x2 u2b = Cp[31] * t2b[r];
            f32x2 ea, eb;
            ea[0] = __builtin_amdgcn_exp2f(u2a[0]);
            ea[1] = __builtin_amdgcn_exp2f(u2a[1]);
            eb[0] = __builtin_amdgcn_exp2f(u2b[0]);
            eb[1] = __builtin_amdgcn_exp2f(u2b[1]);
            f32x2 da = ea + 1.0f, db = eb + 1.0f;
            f32x2 sa, sb;
            sa[0] = __builtin_amdgcn_rcpf(da[0]);
            sa[1] = __builtin_amdgcn_rcpf(da[1]);
            sb[0] = __builtin_amdgcn_rcpf(db[0]);
            sb[1] = __builtin_amdgcn_rcpf(db[1]);
            f32x2 pa = t2a[r] * sa;                    // pk_mul
            f32x2 pb = t2b[r] * sb;
            f32x2 acc = {bb3, 0.0f};
            acc = __builtin_elementwise_fma(pa, Cp[32], acc);
            acc = __builtin_elementwise_fma(pb, Cp[33], acc);
            res[r] = acc[0] + acc[1];
        }
        ((float4*)out)[tid] = make_float4(res[0], res[1], res[2], res[3]);
    } else if (base < rows) {
        // tail (not hit for B = 8388608)
        const float* uw0  = Cs;
        const float* uw1  = Cs + 8;
        const float* ub   = Cs + 16;
        const float* w2f  = Cs + 24;
        const float* bb2  = Cs + 56;
        const float* ncl2 = Cs + 60;
        const float* aw2  = Cs + 64;
        for (long long rr = base; rr < rows; ++rr) {
            float x0 = x[rr * 2 + 0], x1 = x[rr * 2 + 1];
            float h[8];
#pragma unroll
            for (int j = 0; j < 8; ++j) {
                float uu = fmaf(x0, uw0[j], fmaf(x1, uw1[j], ub[j]));
                float s  = __builtin_amdgcn_rcpf(
                               1.0f + __builtin_amdgcn_exp2f(uu));
                h[j] = uu * s;
            }
            float o = bb3;
#pragma unroll
            for (int k = 0; k < 4; ++k) {
                float t = bb2[k];
#pragma unroll
                for (int j = 0; j < 8; ++j) t = fmaf(h[j], w2f[j * 4 + k], t);
                float u2 = ncl2[k] * t;
                float sg = __builtin_amdgcn_rcpf(
                               1.0f + __builtin_amdgcn_exp2f(u2));
                o = fmaf(t * sg, aw2[k], o);
            }
            out[rr] = o;
        }
    }
}

extern "C" void kernel_launch(void* const* d_in, const int* in_sizes, int n_in,
                              void* d_out, int out_size, void* d_ws, size_t ws_size,
                              hipStream_t stream) {
    const float* x  = (const float*)d_in[0];
    const float* W1 = (const float*)d_in[1];
    const float* b1 = (const float*)d_in[2];
    const float* a1 = (const float*)d_in[3];
    const float* c1 = (const float*)d_in[4];
    const float* W2 = (const float*)d_in[5];
    const float* b2 = (const float*)d_in[6];
    const float* a2 = (const float*)d_in[7];
    const float* c2 = (const float*)d_in[8];
    const float* W3 = (const float*)d_in[9];
    const float* b3 = (const float*)d_in[10];
    float* out = (float*)d_out;
    (void)d_ws; (void)ws_size;   // workspace deliberately unused

    int rows  = in_sizes[0] / 2;
    int rows4 = (rows + 3) / 4;            // 4 rows/thread, one-shot
    int block = 256;
    int grid  = (rows4 + block - 1) / block;

    PlaygroundModel_66365834658304_kernel<<<grid, block, 0, stream>>>(
        x, W1, b1, a1, c1, W2, b2, a2, c2, W3, b3, out, rows);
}

// Round 2
// 127.073 us; speedup vs baseline: 1.0338x; 1.0338x over previous
//
#include <hip/hip_runtime.h>

#define NLOG2E -1.44269504088896340736f

typedef float f32x2 __attribute__((ext_vector_type(2)));

// Round 2 structure:
//  - prefold kernel -> d_ws (69 folded floats). H2 confirmed: the harness
//    poisons the 256 MiB workspace regardless of use, so ws costs nothing,
//    and global-C constants get s_load'ed into SGPRs (no LDS latency chains).
//  - main kernel: 8 rows/thread as 4 wave-strided 2-row slots.
//      load  k: x4[waveBase + lane + 64k]  -> 16 B/lane, perfectly coalesced
//      store k: o2[waveBase + lane + 64k]  ->  8 B/lane, perfectly coalesced
//    All 4 loads issued upfront (4 KB in flight per wave) to cover HBM
//    latency; compute is the proven packed-f32x2 body (pk_fma/pk_mul/pk_add,
//    scalar exp2/rcp).
//
// ws layout (floats): [0:8)=uw0 [8:16)=uw1 [16:24)=ub [24:56)=w2f
//                     [56:60)=b2 [60:64)=ncl2 [64:68)=aw2 [68]=bb3

__global__ void prefold_kernel(
    const float* __restrict__ W1, const float* __restrict__ b1,
    const float* __restrict__ a1, const float* __restrict__ c1,
    const float* __restrict__ W2, const float* __restrict__ b2,
    const float* __restrict__ a2, const float* __restrict__ c2,
    const float* __restrict__ W3, const float* __restrict__ b3,
    float* __restrict__ C)
{
    if (threadIdx.x == 0 && blockIdx.x == 0) {
        for (int j = 0; j < 8; ++j) {
            float ncl = c1[j] * NLOG2E;
            C[j]      = W1[j]     * ncl;
            C[8 + j]  = W1[8 + j] * ncl;
            C[16 + j] = b1[j]     * ncl;
            float k1 = a1[j] / ncl;
            for (int k = 0; k < 4; ++k)
                C[24 + j * 4 + k] = W2[j * 4 + k] * k1;
        }
        for (int k = 0; k < 4; ++k) {
            C[56 + k] = b2[k];
            C[60 + k] = c2[k] * NLOG2E;
            C[64 + k] = a2[k] * W3[k];
        }
        C[68] = b3[0];
    }
}

// One 2-row slot: rows (p.x,p.y) and (p.z,p.w) -> f32x2 of outputs.
__device__ __forceinline__ f32x2 moth2(float4 p, const f32x2* __restrict__ Cp,
                                       float bb3)
{
    // stage 1: u-values, 2 rows x 4 j-pairs of pk_fma
    f32x2 u[2][4];
#pragma unroll
    for (int r = 0; r < 2; ++r) {
        float X0 = r ? p.z : p.x;
        float X1 = r ? p.w : p.y;
        f32x2 x0b = {X0, X0};
        f32x2 x1b = {X1, X1};
#pragma unroll
        for (int pj = 0; pj < 4; ++pj)
            u[r][pj] = __builtin_elementwise_fma(
                           x0b, Cp[pj],
                           __builtin_elementwise_fma(x1b, Cp[4 + pj],
                                                     Cp[8 + pj]));
    }

    // stage 2: h_eff = u * rcp(1 + exp2(u)); trans scalar, rest packed
#pragma unroll
    for (int r = 0; r < 2; ++r)
#pragma unroll
        for (int pj = 0; pj < 4; ++pj) {
            f32x2 e;
            e[0] = __builtin_amdgcn_exp2f(u[r][pj][0]);
            e[1] = __builtin_amdgcn_exp2f(u[r][pj][1]);
            f32x2 d = e + 1.0f;                    // pk_add
            f32x2 s;
            s[0] = __builtin_amdgcn_rcpf(d[0]);
            s[1] = __builtin_amdgcn_rcpf(d[1]);
            u[r][pj] *= s;                         // pk_mul, h_eff
        }

    // stages 3+4: layer-2 dot-8, second activation, final reduce
    f32x2 res;
#pragma unroll
    for (int r = 0; r < 2; ++r) {
        f32x2 ta = Cp[28], tb = Cp[29];            // b2 pairs
#pragma unroll
        for (int j = 0; j < 8; ++j) {
            float hj = u[r][j >> 1][j & 1];
            f32x2 hb = {hj, hj};
            ta = __builtin_elementwise_fma(hb, Cp[12 + j * 2 + 0], ta);
            tb = __builtin_elementwise_fma(hb, Cp[12 + j * 2 + 1], tb);
        }
        f32x2 u2a = Cp[30] * ta;                   // ncl2 pairs
        f32x2 u2b = Cp[31] * tb;
        f32x2 ea, eb;
        ea[0] = __builtin_amdgcn_exp2f(u2a[0]);
        ea[1] = __builtin_amdgcn_exp2f(u2a[1]);
        eb[0] = __builtin_amdgcn_exp2f(u2b[0]);
        eb[1] = __builtin_amdgcn_exp2f(u2b[1]);
        f32x2 da = ea + 1.0f, db = eb + 1.0f;
        f32x2 sa, sb;
        sa[0] = __builtin_amdgcn_rcpf(da[0]);
        sa[1] = __builtin_amdgcn_rcpf(da[1]);
        sb[0] = __builtin_amdgcn_rcpf(db[0]);
        sb[1] = __builtin_amdgcn_rcpf(db[1]);
        f32x2 pa = ta * sa;                        // pk_mul
        f32x2 pb = tb * sb;
        f32x2 acc = {bb3, 0.0f};
        acc = __builtin_elementwise_fma(pa, Cp[32], acc);
        acc = __builtin_elementwise_fma(pb, Cp[33], acc);
        res[r] = acc[0] + acc[1];
    }
    return res;
}

__global__ __launch_bounds__(256, 4) void PlaygroundModel_66365834658304_kernel(
    const float* __restrict__ x, const float* __restrict__ C,
    float* __restrict__ out, int rows)
{
    const f32x2* Cp = (const f32x2*)C;
    float bb3 = C[68];

    int g = blockIdx.x * blockDim.x + threadIdx.x;
    int lane = g & 63;
    long long idx0 = (long long)(g >> 6) * 256 + lane;  // wave-strided slot 0
    long long n4f  = (long long)rows >> 1;              // full 2-row groups

    const float4* x4 = (const float4*)x;
    f32x2* o2 = (f32x2*)out;

    if (idx0 + 192 < n4f) {
        // all 4 loads upfront: 4 KB in flight per wave, each perfectly
        // coalesced (16 B/lane, lane-consecutive)
        float4 P0 = x4[idx0];
        float4 P1 = x4[idx0 + 64];
        float4 P2 = x4[idx0 + 128];
        float4 P3 = x4[idx0 + 192];
        o2[idx0]       = moth2(P0, Cp, bb3);
        o2[idx0 + 64]  = moth2(P1, Cp, bb3);
        o2[idx0 + 128] = moth2(P2, Cp, bb3);
        o2[idx0 + 192] = moth2(P3, Cp, bb3);
    } else {
        // boundary wave: scalar per-row fallback (not hit for B = 8388608
        // fast path, only the final partial wave lands here)
        const float* uw0  = C;
        const float* uw1  = C + 8;
        const float* ub   = C + 16;
        const float* w2f  = C + 24;
        const float* bb2  = C + 56;
        const float* ncl2 = C + 60;
        const float* aw2  = C + 64;
#pragma unroll
        for (int k = 0; k < 4; ++k) {
            long long idx = idx0 + 64 * k;
            long long r0 = idx * 2;
            for (long long rr = r0; rr < r0 + 2 && rr < rows; ++rr) {
                float x0 = x[rr * 2 + 0], x1 = x[rr * 2 + 1];
                float h[8];
#pragma unroll
                for (int j = 0; j < 8; ++j) {
                    float uu = fmaf(x0, uw0[j], fmaf(x1, uw1[j], ub[j]));
                    float s  = __builtin_amdgcn_rcpf(
                                   1.0f + __builtin_amdgcn_exp2f(uu));
                    h[j] = uu * s;
                }
                float o = bb3;
#pragma unroll
                for (int kk = 0; kk < 4; ++kk) {
                    float t = bb2[kk];
#pragma unroll
                    for (int j = 0; j < 8; ++j)
                        t = fmaf(h[j], w2f[j * 4 + kk], t);
                    float u2 = ncl2[kk] * t;
                    float sg = __builtin_amdgcn_rcpf(
                                   1.0f + __builtin_amdgcn_exp2f(u2));
                    o = fmaf(t * sg, aw2[kk], o);
                }
                out[rr] = o;
            }
        }
    }
}

extern "C" void kernel_launch(void* const* d_in, const int* in_sizes, int n_in,
                              void* d_out, int out_size, void* d_ws, size_t ws_size,
                              hipStream_t stream) {
    const float* x  = (const float*)d_in[0];
    const float* W1 = (const float*)d_in[1];
    const float* b1 = (const float*)d_in[2];
    const float* a1 = (const float*)d_in[3];
    const float* c1 = (const float*)d_in[4];
    const float* W2 = (const float*)d_in[5];
    const float* b2 = (const float*)d_in[6];
    const float* a2 = (const float*)d_in[7];
    const float* c2 = (const float*)d_in[8];
    const float* W3 = (const float*)d_in[9];
    const float* b3 = (const float*)d_in[10];
    float* out = (float*)d_out;
    float* C   = (float*)d_ws;

    prefold_kernel<<<1, 64, 0, stream>>>(W1, b1, a1, c1, W2, b2, a2, c2,
                                         W3, b3, C);

    int rows = in_sizes[0] / 2;
    long long n4    = ((long long)rows + 1) / 2;   // 2-row groups (incl. partial)
    long long waves = (n4 + 255) / 256;            // 256 groups per wave
    long long thr   = waves * 64;
    int block = 256;
    long long grid = (thr + block - 1) / block;
    if (grid < 1) grid = 1;

    PlaygroundModel_66365834658304_kernel<<<(int)grid, block, 0, stream>>>(
        x, C, out, rows);
}